// Round 10
// baseline (116.930 us; speedup 1.0000x reference)
//
#include <hip/hip_runtime.h>
#include <math.h>

#define FDIM 128
#define NP 32                 // CSR partition blocks
#define NMAX 10240            // LDS capacity (N=10000)
static constexpr float SC2 = 0.17677669529663687f * 1.4426950408889634f; // (1/sqrt(32))*log2(e)
static constexpr float LN_EPS = 1e-5f;

__device__ __forceinline__ unsigned short f2bf(float f) {
    unsigned u = __float_as_uint(f);
    unsigned r = u + 0x7FFFu + ((u >> 16) & 1u);   // RNE
    return (unsigned short)(r >> 16);
}

// ---------------------------------------------------------------------------
// K1: fused 4-way GEMM (blockIdx.y 0..3) + LDS histogram (y==4, x<NP).
// Q bf16 -> Qu[n][128]; K,V bf16 interleaved KVu[n][256]; R fp32.
// ---------------------------------------------------------------------------
__global__ __launch_bounds__(256) void gemm_hist_kernel(
    const float* __restrict__ nodes,
    const float* __restrict__ Wq, const float* __restrict__ Wk,
    const float* __restrict__ Wv, const float* __restrict__ Wr,
    const float* __restrict__ br,
    unsigned short* __restrict__ Qu, unsigned short* __restrict__ KVu,
    float* __restrict__ Rb, int N,
    const int* __restrict__ dst, int* __restrict__ bh, int E, int C)
{
    __shared__ __align__(16) char smem[NMAX * 4];   // 40KB: union of h[] / As[]
    const int tid = threadIdx.x;
    const int wi = blockIdx.y;

    if (wi == 4) {                    // ---- histogram partition ----
        const int p = blockIdx.x;
        if (p >= NP) return;
        int* h = (int*)smem;
        for (int i = tid; i < N; i += 256) h[i] = 0;
        __syncthreads();
        const int lo = p * C;
        const int hi = min(lo + C, E);
        const int n = hi - lo;
        if (n > 0) {
            if (((lo | E) & 3) == 0) {
                const int4* d4 = (const int4*)(dst + lo);
                const int n4 = n >> 2;
                for (int i = tid; i < n4; i += 256) {
                    int4 d = d4[i];
                    atomicAdd(&h[d.x], 1); atomicAdd(&h[d.y], 1);
                    atomicAdd(&h[d.z], 1); atomicAdd(&h[d.w], 1);
                }
                for (int i = lo + (n4 << 2) + tid; i < hi; i += 256)
                    atomicAdd(&h[dst[i]], 1);
            } else {
                for (int i = lo + tid; i < hi; i += 256)
                    atomicAdd(&h[dst[i]], 1);
            }
        }
        __syncthreads();
        for (int i = tid; i < N; i += 256) bh[p * N + i] = h[i];
        return;
    }

    // ---- GEMM partition ----
    float (*As)[FDIM] = (float(*)[FDIM])smem;       // 32KB of the 40KB
    const int row0 = blockIdx.x * 64;
    const float* __restrict__ W = (wi == 0) ? Wq : (wi == 1) ? Wk : (wi == 2) ? Wv : Wr;

    #pragma unroll
    for (int i = 0; i < 8; ++i) {
        int idx = tid + i * 256;          // 0..2047 float4s
        int r = idx >> 5, c4 = idx & 31;
        int gr = row0 + r;
        float4 v = make_float4(0.f, 0.f, 0.f, 0.f);
        if (gr < N) v = *reinterpret_cast<const float4*>(&nodes[(size_t)gr * FDIM + c4 * 4]);
        *reinterpret_cast<float4*>(&As[r][c4 * 4]) = v;
    }
    __syncthreads();

    const int cg = tid & 31;
    const int rg = tid >> 5;
    const int c0 = cg * 4;
    const int r0 = rg * 8;

    float acc[8][4];
    #pragma unroll
    for (int i = 0; i < 8; ++i)
        #pragma unroll
        for (int j = 0; j < 4; ++j) acc[i][j] = 0.f;

    #pragma unroll 2
    for (int k = 0; k < FDIM; k += 2) {
        const float4 wA = *reinterpret_cast<const float4*>(&W[k * FDIM + c0]);
        const float4 wB = *reinterpret_cast<const float4*>(&W[(k + 1) * FDIM + c0]);
        float2 a[8];
        #pragma unroll
        for (int i = 0; i < 8; ++i)
            a[i] = *reinterpret_cast<const float2*>(&As[r0 + i][k]);
        #pragma unroll
        for (int i = 0; i < 8; ++i) {
            acc[i][0] += a[i].x * wA.x + a[i].y * wB.x;
            acc[i][1] += a[i].x * wA.y + a[i].y * wB.y;
            acc[i][2] += a[i].x * wA.z + a[i].y * wB.z;
            acc[i][3] += a[i].x * wA.w + a[i].y * wB.w;
        }
    }

    float4 bias = make_float4(0.f, 0.f, 0.f, 0.f);
    if (wi == 3) bias = *reinterpret_cast<const float4*>(&br[c0]);

    #pragma unroll
    for (int i = 0; i < 8; ++i) {
        int gr = row0 + r0 + i;
        if (gr >= N) continue;
        if (wi == 3) {
            float4 o = make_float4(acc[i][0] + bias.x, acc[i][1] + bias.y,
                                   acc[i][2] + bias.z, acc[i][3] + bias.w);
            *reinterpret_cast<float4*>(&Rb[(size_t)gr * 128 + c0]) = o;
        } else {
            ushort4 o;
            o.x = f2bf(acc[i][0]); o.y = f2bf(acc[i][1]);
            o.z = f2bf(acc[i][2]); o.w = f2bf(acc[i][3]);
            unsigned short* dp;
            if (wi == 0)      dp = &Qu[(size_t)gr * 128 + c0];
            else              dp = &KVu[(size_t)gr * 256 + ((wi == 2) ? 128 : 0) + c0];
            *reinterpret_cast<ushort4*>(dp) = o;
        }
    }
}

// ---------------------------------------------------------------------------
// K2a: deg[d] = sum_p bh[p][d]
// ---------------------------------------------------------------------------
__global__ __launch_bounds__(256) void deg_kernel(
    const int* __restrict__ bh, int* __restrict__ deg, int N)
{
    const int d = blockIdx.x * 256 + threadIdx.x;
    if (d < N) {
        int s = 0;
        #pragma unroll
        for (int p = 0; p < NP; ++p) s += bh[p * N + d];
        deg[d] = s;
    }
}

// ---------------------------------------------------------------------------
// K2b: single-block exclusive scan of deg -> rowptr
// ---------------------------------------------------------------------------
__global__ __launch_bounds__(1024) void scan_kernel(
    const int* __restrict__ deg, int* __restrict__ rowptr, int N)
{
    __shared__ int tot[NMAX];
    __shared__ int csum[1024];
    const int tid = threadIdx.x;

    for (int d = tid; d < N; d += 1024) tot[d] = deg[d];
    __syncthreads();

    const int CH = (N + 1023) / 1024;
    const int b = tid * CH;
    const int e = min(b + CH, N);
    int s = 0;
    for (int i = b; i < e; ++i) s += tot[i];
    csum[tid] = s;
    __syncthreads();
    for (int off = 1; off < 1024; off <<= 1) {
        int t = (tid >= off) ? csum[tid - off] : 0;
        __syncthreads();
        csum[tid] += t;
        __syncthreads();
    }
    int run = csum[tid] - s;
    for (int i = b; i < e; ++i) {
        const int t = tot[i];
        rowptr[i] = run;
        run += t;
    }
    if (tid == 1023) rowptr[N] = csum[1023];
}

// ---------------------------------------------------------------------------
// K2c: bh counts -> per-partition exclusive bases, in place.
// ---------------------------------------------------------------------------
__global__ __launch_bounds__(256) void base_kernel(
    int* __restrict__ bh, const int* __restrict__ rowptr, int N)
{
    const int d = blockIdx.x * 256 + threadIdx.x;
    if (d < N) {
        int c = rowptr[d];
        #pragma unroll
        for (int p = 0; p < NP; ++p) {
            const int cnt = bh[p * N + d];
            bh[p * N + d] = c;
            c += cnt;
        }
    }
}

// ---------------------------------------------------------------------------
// K3: scatter src ids into CSR slots (LDS cursors).
// ---------------------------------------------------------------------------
__global__ __launch_bounds__(256) void scatter_kernel(
    const int* __restrict__ src, const int* __restrict__ dst,
    const int* __restrict__ base, int* __restrict__ ssrc,
    int N, int E, int C)
{
    __shared__ int cur[NMAX];
    const int p = blockIdx.x, tid = threadIdx.x;
    for (int d = tid; d < N; d += 256) cur[d] = base[p * N + d];
    __syncthreads();

    const int lo = p * C;
    const int hi = min(lo + C, E);
    const int n = hi - lo;
    if (n <= 0) return;

    if (((lo | E) & 3) == 0) {
        const int4* s4 = (const int4*)(src + lo);
        const int4* d4 = (const int4*)(dst + lo);
        const int n4 = n >> 2;
        for (int i = tid; i < n4; i += 256) {
            int4 s = s4[i];
            int4 d = d4[i];
            int p0 = atomicAdd(&cur[d.x], 1); ssrc[p0] = s.x;
            int p1 = atomicAdd(&cur[d.y], 1); ssrc[p1] = s.y;
            int p2 = atomicAdd(&cur[d.z], 1); ssrc[p2] = s.z;
            int p3 = atomicAdd(&cur[d.w], 1); ssrc[p3] = s.w;
        }
        for (int i = lo + (n4 << 2) + tid; i < hi; i += 256) {
            int pos = atomicAdd(&cur[dst[i]], 1); ssrc[pos] = src[i];
        }
    } else {
        for (int i = lo + tid; i < hi; i += 256) {
            int pos = atomicAdd(&cur[dst[i]], 1); ssrc[pos] = src[i];
        }
    }
}

// ---------------------------------------------------------------------------
// K4: quarter-wave (16 lanes) per node; lane owns 8 dims (uint4 bf16 loads).
// Head = 4-lane group (dot reduce = xor 1,2). 4-edge batches, pipelined
// gathers + two-deep index prefetch. Residual + LayerNorm fused.
// ---------------------------------------------------------------------------
__global__ __launch_bounds__(256) void agg_kernel(
    const unsigned short* __restrict__ Qu, const unsigned short* __restrict__ KVu,
    const float* __restrict__ Rb,
    const int* __restrict__ rowptr, const int* __restrict__ ssrc,
    const float* __restrict__ gamma, const float* __restrict__ beta,
    float* __restrict__ out, int N)
{
    const int wave = threadIdx.x >> 6;
    const int lane = threadIdx.x & 63;
    const int qtr = lane >> 4;
    const int lq = lane & 15;
    const int n = blockIdx.x * 16 + wave * 4 + qtr;
    if (n >= N) return;
    const int d0 = lq * 8;

    // unpack q (8 bf16)
    const uint4 qu = *reinterpret_cast<const uint4*>(&Qu[(size_t)n * 128 + d0]);
    const float qf0 = __uint_as_float(qu.x << 16), qf1 = __uint_as_float(qu.x & 0xFFFF0000u);
    const float qf2 = __uint_as_float(qu.y << 16), qf3 = __uint_as_float(qu.y & 0xFFFF0000u);
    const float qf4 = __uint_as_float(qu.z << 16), qf5 = __uint_as_float(qu.z & 0xFFFF0000u);
    const float qf6 = __uint_as_float(qu.w << 16), qf7 = __uint_as_float(qu.w & 0xFFFF0000u);

    const int beg = rowptr[n];
    const int end = rowptr[n + 1];

    float4 A0a = make_float4(0.f, 0.f, 0.f, 0.f), A0b = A0a;
    float4 A1a = A0a, A1b = A0a, A2a = A0a, A2b = A0a, A3a = A0a, A3b = A0a;
    float L0 = 0.f, L1 = 0.f, L2 = 0.f, L3 = 0.f;

#define GATHER(S, NK, NV)                                                     \
    {                                                                         \
        const unsigned short* bp = &KVu[(size_t)(S) * 256 + d0];              \
        NK = *reinterpret_cast<const uint4*>(bp);                             \
        NV = *reinterpret_cast<const uint4*>(bp + 128);                       \
    }
#define STEP(KU, VU, Aa, Ab, L)                                               \
    {                                                                         \
        const float k0 = __uint_as_float((KU).x << 16), k1 = __uint_as_float((KU).x & 0xFFFF0000u); \
        const float k2 = __uint_as_float((KU).y << 16), k3 = __uint_as_float((KU).y & 0xFFFF0000u); \
        const float k4 = __uint_as_float((KU).z << 16), k5 = __uint_as_float((KU).z & 0xFFFF0000u); \
        const float k6 = __uint_as_float((KU).w << 16), k7 = __uint_as_float((KU).w & 0xFFFF0000u); \
        float p = qf0 * k0 + qf1 * k1 + qf2 * k2 + qf3 * k3                   \
                + qf4 * k4 + qf5 * k5 + qf6 * k6 + qf7 * k7;                  \
        p += __shfl_xor(p, 1);                                                \
        p += __shfl_xor(p, 2);                                                \
        const float e1 = exp2f(p * SC2);                                      \
        const float v0 = __uint_as_float((VU).x << 16), v1 = __uint_as_float((VU).x & 0xFFFF0000u); \
        const float v2 = __uint_as_float((VU).y << 16), v3 = __uint_as_float((VU).y & 0xFFFF0000u); \
        const float v4 = __uint_as_float((VU).z << 16), v5 = __uint_as_float((VU).z & 0xFFFF0000u); \
        const float v6 = __uint_as_float((VU).w << 16), v7 = __uint_as_float((VU).w & 0xFFFF0000u); \
        Aa.x += e1 * v0; Aa.y += e1 * v1; Aa.z += e1 * v2; Aa.w += e1 * v3;   \
        Ab.x += e1 * v4; Ab.y += e1 * v5; Ab.z += e1 * v6; Ab.w += e1 * v7;   \
        L += e1;                                                              \
    }

    uint4 nk0, nv0, nk1, nv1, nk2, nv2, nk3, nv3;
    int j = beg;
    const int nb = (end - beg) >> 2;
    if (nb > 0) {
        int c0i = ssrc[j], c1i = ssrc[j + 1], c2i = ssrc[j + 2], c3i = ssrc[j + 3];
        GATHER(c0i, nk0, nv0); GATHER(c1i, nk1, nv1);
        GATHER(c2i, nk2, nv2); GATHER(c3i, nk3, nv3);
        // prefetch next indices (ssrc padded by 8 -> safe)
        int x0 = ssrc[j + 4], x1 = ssrc[j + 5], x2 = ssrc[j + 6], x3 = ssrc[j + 7];
        for (int bi = 1; bi < nb; ++bi) {
            const uint4 ck0 = nk0, cv0 = nv0, ck1 = nk1, cv1 = nv1;
            const uint4 ck2 = nk2, cv2 = nv2, ck3 = nk3, cv3 = nv3;
            c0i = x0; c1i = x1; c2i = x2; c3i = x3;
            const int nbase = j + (bi + 1) * 4;           // prefetch (padded)
            x0 = ssrc[nbase]; x1 = ssrc[nbase + 1];
            x2 = ssrc[nbase + 2]; x3 = ssrc[nbase + 3];
            GATHER(c0i, nk0, nv0); GATHER(c1i, nk1, nv1);
            GATHER(c2i, nk2, nv2); GATHER(c3i, nk3, nv3);
            STEP(ck0, cv0, A0a, A0b, L0);
            STEP(ck1, cv1, A1a, A1b, L1);
            STEP(ck2, cv2, A2a, A2b, L2);
            STEP(ck3, cv3, A3a, A3b, L3);
        }
        STEP(nk0, nv0, A0a, A0b, L0);
        STEP(nk1, nv1, A1a, A1b, L1);
        STEP(nk2, nv2, A2a, A2b, L2);
        STEP(nk3, nv3, A3a, A3b, L3);
        j = beg + nb * 4;
    }
    for (; j < end; ++j) {
        const int s0 = ssrc[j];
        uint4 k0u, v0u;
        GATHER(s0, k0u, v0u);
        STEP(k0u, v0u, A0a, A0b, L0);
    }
#undef GATHER
#undef STEP

    const float L = (L0 + L1) + (L2 + L3);
    const float inv = 1.f / (L + 1e-12f);          // empty segment -> x = r
    const float4 ra = *reinterpret_cast<const float4*>(&Rb[(size_t)n * 128 + d0]);
    const float4 rb = *reinterpret_cast<const float4*>(&Rb[(size_t)n * 128 + d0 + 4]);
    float xa0 = ((A0a.x + A1a.x) + (A2a.x + A3a.x)) * inv + ra.x;
    float xa1 = ((A0a.y + A1a.y) + (A2a.y + A3a.y)) * inv + ra.y;
    float xa2 = ((A0a.z + A1a.z) + (A2a.z + A3a.z)) * inv + ra.z;
    float xa3 = ((A0a.w + A1a.w) + (A2a.w + A3a.w)) * inv + ra.w;
    float xb0 = ((A0b.x + A1b.x) + (A2b.x + A3b.x)) * inv + rb.x;
    float xb1 = ((A0b.y + A1b.y) + (A2b.y + A3b.y)) * inv + rb.y;
    float xb2 = ((A0b.z + A1b.z) + (A2b.z + A3b.z)) * inv + rb.z;
    float xb3 = ((A0b.w + A1b.w) + (A2b.w + A3b.w)) * inv + rb.w;

    // LayerNorm over 16 lanes x 8 dims
    float s1v = (xa0 + xa1 + xa2 + xa3) + (xb0 + xb1 + xb2 + xb3);
    float s2v = xa0 * xa0 + xa1 * xa1 + xa2 * xa2 + xa3 * xa3
              + xb0 * xb0 + xb1 * xb1 + xb2 * xb2 + xb3 * xb3;
    #pragma unroll
    for (int off = 8; off; off >>= 1) {
        s1v += __shfl_xor(s1v, off);
        s2v += __shfl_xor(s2v, off);
    }
    const float mu = s1v * (1.f / 128.f);
    float var = s2v * (1.f / 128.f) - mu * mu;
    var = fmaxf(var, 0.f);
    const float rs = rsqrtf(var + LN_EPS);

    const float4 ga = *reinterpret_cast<const float4*>(&gamma[d0]);
    const float4 gb = *reinterpret_cast<const float4*>(&gamma[d0 + 4]);
    const float4 ba = *reinterpret_cast<const float4*>(&beta[d0]);
    const float4 bb = *reinterpret_cast<const float4*>(&beta[d0 + 4]);
    float4 oa, ob;
    oa.x = ga.x * (xa0 - mu) * rs + ba.x;
    oa.y = ga.y * (xa1 - mu) * rs + ba.y;
    oa.z = ga.z * (xa2 - mu) * rs + ba.z;
    oa.w = ga.w * (xa3 - mu) * rs + ba.w;
    ob.x = gb.x * (xb0 - mu) * rs + bb.x;
    ob.y = gb.y * (xb1 - mu) * rs + bb.y;
    ob.z = gb.z * (xb2 - mu) * rs + bb.z;
    ob.w = gb.w * (xb3 - mu) * rs + bb.w;
    *reinterpret_cast<float4*>(&out[(size_t)n * 128 + d0]) = oa;
    *reinterpret_cast<float4*>(&out[(size_t)n * 128 + d0 + 4]) = ob;
}

// ---------------------------------------------------------------------------
extern "C" void kernel_launch(void* const* d_in, const int* in_sizes, int n_in,
                              void* d_out, int out_size, void* d_ws, size_t ws_size,
                              hipStream_t stream)
{
    const float* nodes = (const float*)d_in[0];
    const float* W_Q   = (const float*)d_in[1];
    const float* W_K   = (const float*)d_in[2];
    const float* W_V   = (const float*)d_in[3];
    const float* W_res = (const float*)d_in[4];
    const float* b_res = (const float*)d_in[5];
    const float* gamma = (const float*)d_in[6];
    const float* beta  = (const float*)d_in[7];
    const int*   eidx  = (const int*)d_in[8];

    const int N = in_sizes[0] / FDIM;
    const int E = in_sizes[8] / 2;
    const int* src = eidx;
    const int* dst = eidx + E;

    float* out = (float*)d_out;

    // workspace carve
    unsigned short* KVu = (unsigned short*)d_ws;              // N*256 bf16
    unsigned short* Qu  = KVu + (size_t)N * 256;              // N*128 bf16
    float* Rb = (float*)(Qu + (size_t)N * 128);               // N*128 f32
    int* bh     = (int*)(Rb + (size_t)N * 128);               // NP*N (counts -> bases)
    int* rowptr = bh + (size_t)NP * N;                        // N+1
    int* deg    = rowptr + (N + 1);                           // N
    int* ssrc   = deg + N;                                    // E + 8 (pad for prefetch)

    const int C = (((E + NP - 1) / NP) + 3) & ~3;             // chunk, mult of 4
    const int nG = (N + 63) / 64;
    const int nB = (N + 255) / 256;

    dim3 ggrid(nG, 5);                                        // y==4 -> histogram
    gemm_hist_kernel<<<ggrid, 256, 0, stream>>>(nodes, W_Q, W_K, W_V, W_res, b_res,
                                                Qu, KVu, Rb, N, dst, bh, E, C);
    deg_kernel<<<nB, 256, 0, stream>>>(bh, deg, N);
    scan_kernel<<<1, 1024, 0, stream>>>(deg, rowptr, N);
    base_kernel<<<nB, 256, 0, stream>>>(bh, rowptr, N);
    scatter_kernel<<<NP, 256, 0, stream>>>(src, dst, bh, ssrc, N, E, C);
    agg_kernel<<<(N + 15) / 16, 256, 0, stream>>>(Qu, KVu, Rb, rowptr, ssrc,
                                                  gamma, beta, out, N);
}